// Round 1
// baseline (537.044 us; speedup 1.0000x reference)
//
#include <hip/hip_runtime.h>

// CapsuleTransformConv: out[b,oh,ow,n,fc] = sum_a x[b,oh+ki,ow+kj,c,a] * M[n,a,fc]
//   n = (ki*3+kj)*32 + c ; fc in [0,512)
// Shapes: x[4,16,16,32,16] f32 (2MB), M[288,16,512] f32 (9.4MB),
//         out[4,14,14,288,512] f32 (462MB)  -> HBM-write-bound (~73us floor).

#define KK      3
#define CIN     32
#define IN_ATOM 16
#define FC      512            // FILTER*ATOM
#define OH      14
#define OW      14
#define BATCH   4
#define HH      16
#define WW      16
#define NN      (KK*KK*CIN)    // 288

__global__ __launch_bounds__(128, 2)
void caps_transform_kernel(const float* __restrict__ x,
                           const float* __restrict__ m,
                           float* __restrict__ out)
{
    const int n   = blockIdx.x;            // 0..287  (capsule index)
    const int b   = blockIdx.y;            // 0..3
    const int fc0 = threadIdx.x * 4;       // each thread owns 4 consecutive fc

    const int ki = n / (KK * CIN);         // kernel row
    const int kj = (n / CIN) % KK;         // kernel col
    const int c  = n % CIN;                // input channel

    // Load this thread's matrix slice M[n, 0..15, fc0..fc0+3] into registers.
    float4 mm[IN_ATOM];
    const float* mp = m + ((long)n * IN_ATOM) * FC + fc0;
#pragma unroll
    for (int a = 0; a < IN_ATOM; ++a)
        mm[a] = *reinterpret_cast<const float4*>(mp + (long)a * FC);

    // x base for (b, c): x[b, h, w, c, a] = xb[ (h*WW + w) * CIN*IN_ATOM + a ]
    const float* xb = x + ((long)b * HH * WW * CIN + (long)c) * IN_ATOM;
    // out base for (b, n, fc0); per-position stride NN*FC
    float* ob = out + ((long)b * OH * OW * NN + n) * (long)FC + fc0;

    for (int oh = 0; oh < OH; ++oh) {
        const float* xrow = xb + (long)(oh + ki) * WW * CIN * IN_ATOM;
        float* orow = ob + (long)oh * OW * (NN * FC);
        for (int ow = 0; ow < OW; ++ow) {
            const float* xp = xrow + (long)(ow + kj) * (CIN * IN_ATOM);
            float4 acc = make_float4(0.f, 0.f, 0.f, 0.f);
#pragma unroll
            for (int a = 0; a < IN_ATOM; ++a) {
                const float xv = xp[a];     // wave-uniform -> s_load
                acc.x += xv * mm[a].x;
                acc.y += xv * mm[a].y;
                acc.z += xv * mm[a].z;
                acc.w += xv * mm[a].w;
            }
            *reinterpret_cast<float4*>(orow + (long)ow * (NN * FC)) = acc;
        }
    }
}

extern "C" void kernel_launch(void* const* d_in, const int* in_sizes, int n_in,
                              void* d_out, int out_size, void* d_ws, size_t ws_size,
                              hipStream_t stream)
{
    const float* x = (const float*)d_in[0];
    const float* m = (const float*)d_in[1];
    float* out = (float*)d_out;

    dim3 grid(NN, BATCH);   // 288 x 4 = 1152 blocks
    dim3 block(128);        // 128 threads * 4 fc = 512 fc
    caps_transform_kernel<<<grid, block, 0, stream>>>(x, m, out);
}